// Round 1
// baseline (106.135 us; speedup 1.0000x reference)
//
#include <hip/hip_runtime.h>
#include <math.h>

// Problem constants (from setup_inputs: B=8, P=512, Q=4096, H=W=512)
#define BB   8
#define PP   512
#define QQ   4096
#define NPTS (BB * PP)   // 4096 matched points
#define RADF 45.0f       // truncation radius of gaussian patch
#define INV2S2 (1.0f / 450.0f)  // 1/(2*15^2)

// ---------------------------------------------------------------------------
// block-wide sum reduction (blockDim.x multiple of 64, <=512). Result valid at
// threadIdx.x == 0. Safe to call repeatedly with the same sbuf.
__device__ inline float block_reduce(float v, float* sbuf) {
#pragma unroll
    for (int off = 32; off > 0; off >>= 1) v += __shfl_down(v, off);
    const int lane = threadIdx.x & 63;
    const int wid  = threadIdx.x >> 6;
    __syncthreads();                 // protect sbuf against prior call reuse
    if (lane == 0) sbuf[wid] = v;
    __syncthreads();
    float r = (threadIdx.x < (blockDim.x >> 6)) ? sbuf[threadIdx.x] : 0.0f;
    if (wid == 0) {
#pragma unroll
        for (int off = 32; off > 0; off >>= 1) r += __shfl_down(r, off);
    }
    return r;
}

// ---------------------------------------------------------------------------
// ws layout: [0, BB*QQ) int flags ; then 4 floats accum {ce_num, ce_den, focal}
__global__ void k_zero(int* __restrict__ flags, float* __restrict__ acc) {
    int i = blockIdx.x * blockDim.x + threadIdx.x;
    if (i < BB * QQ) flags[i] = 0;
    if (i < 4) acc[i] = 0.0f;
}

__global__ void k_scatter(const int* __restrict__ src_idx, int* __restrict__ flags) {
    int n = blockIdx.x * blockDim.x + threadIdx.x;
    if (n < NPTS) {
        int b = n / PP;                 // src_idx is (B, P) row-major
        int q = src_idx[n];
        flags[b * QQ + q] = 1;
    }
}

// classification loss: weighted CE over (B, Q, 2) logits
__global__ void k_ce(const float2* __restrict__ logits, const int* __restrict__ flags,
                     float* __restrict__ acc) {
    __shared__ float sbuf[8];
    int i = blockIdx.x * blockDim.x + threadIdx.x;   // grid sized exactly B*Q
    float2 l = logits[i];
    int tc = flags[i];
    float mx  = fmaxf(l.x, l.y);
    float lse = mx + log1pf(expf(-fabsf(l.x - l.y)));
    float nll = lse - (tc ? l.y : l.x);
    float w   = tc ? 1.0f : 0.5f;
    float s_num = block_reduce(w * nll, sbuf);
    float s_den = block_reduce(w, sbuf);
    if (threadIdx.x == 0) {
        atomicAdd(&acc[0], s_num);
        atomicAdd(&acc[1], s_den);
    }
}

// points loss: density = exp(-min d^2 / 2s^2) over same-batch target points
// within the 91x91 truncation window; bilinear sample at predicted points;
// focal transform; sum.
__global__ void k_points(const float* __restrict__ tpts, const float* __restrict__ spts,
                         const int* __restrict__ ihp, const int* __restrict__ iwp,
                         float* __restrict__ acc) {
    __shared__ float spx[PP];
    __shared__ float spy[PP];
    __shared__ float sbuf[8];
    const int b = blockIdx.x;
    const float fH = (float)ihp[0];
    const float fW = (float)iwp[0];

    // stage this batch's rounded/clipped target pixel coords in LDS
    for (int m = threadIdx.x; m < PP; m += blockDim.x) {
        float t0 = tpts[(b * PP + m) * 2 + 0];
        float t1 = tpts[(b * PP + m) * 2 + 1];
        // px = clip(round((t0/img_h)*img_w)), py = clip(round((t1/img_w)*img_h))
        float fx = rintf(t0 / fH * fW);   // rintf = round-half-even, matches jnp.round
        float fy = rintf(t1 / fW * fH);
        spx[m] = fminf(fmaxf(fx, 0.0f), fW - 1.0f);
        spy[m] = fminf(fmaxf(fy, 0.0f), fH - 1.0f);
    }
    __syncthreads();

    const int n = b * PP + blockIdx.y * blockDim.x + threadIdx.x;  // one sample/thread
    float sx = fminf(fmaxf(spts[n * 2 + 0] * fW, 0.0f), fW - 1.0f);
    float sy = fminf(fmaxf(spts[n * 2 + 1] * fH, 0.0f), fH - 1.0f);
    float x0 = floorf(sx), y0 = floorf(sy);
    float x1 = fminf(x0 + 1.0f, fW - 1.0f);
    float y1 = fminf(y0 + 1.0f, fH - 1.0f);
    float wx = sx - x0, wy = sy - y0;

    float m00 = 1e30f, m01 = 1e30f, m10 = 1e30f, m11 = 1e30f;
    for (int m = 0; m < PP; ++m) {
        float px = spx[m], py = spy[m];   // LDS broadcast (wave-uniform addr)
        float dx0 = x0 - px, dx1 = x1 - px;
        float dy0 = y0 - py, dy1 = y1 - py;
        float cx0 = (fabsf(dx0) <= RADF) ? dx0 * dx0 : 1e30f;
        float cx1 = (fabsf(dx1) <= RADF) ? dx1 * dx1 : 1e30f;
        float cy0 = (fabsf(dy0) <= RADF) ? dy0 * dy0 : 1e30f;
        float cy1 = (fabsf(dy1) <= RADF) ? dy1 * dy1 : 1e30f;
        m00 = fminf(m00, cx0 + cy0);
        m01 = fminf(m01, cx1 + cy0);
        m10 = fminf(m10, cx0 + cy1);
        m11 = fminf(m11, cx1 + cy1);
    }
    float v00 = (m00 < 1e29f) ? expf(-m00 * INV2S2) : 0.0f;
    float v01 = (m01 < 1e29f) ? expf(-m01 * INV2S2) : 0.0f;
    float v10 = (m10 < 1e29f) ? expf(-m10 * INV2S2) : 0.0f;
    float v11 = (m11 < 1e29f) ? expf(-m11 * INV2S2) : 0.0f;

    float p = v00 * (1.0f - wx) * (1.0f - wy) + v01 * wx * (1.0f - wy)
            + v10 * (1.0f - wx) * wy          + v11 * wx * wy;
    float om  = 1.0f - p;
    float raw = -(om * om) * logf(fmaxf(p, 1e-6f));

    float s = block_reduce(raw, sbuf);
    if (threadIdx.x == 0) atomicAdd(&acc[2], s);
}

__global__ void k_final(const float* __restrict__ acc, float* __restrict__ out) {
    // total = 1.0 * ce_num/ce_den + 5.0 * (0.1 * focal_sum / N)
    out[0] = acc[0] / acc[1] + 0.5f * acc[2] / (float)NPTS;
}

// ---------------------------------------------------------------------------
extern "C" void kernel_launch(void* const* d_in, const int* in_sizes, int n_in,
                              void* d_out, int out_size, void* d_ws, size_t ws_size,
                              hipStream_t stream) {
    const float*  tpts    = (const float*)d_in[0];   // target_points (B*P, 2)
    const float*  spts    = (const float*)d_in[1];   // src_points    (B*P, 2)
    const float2* logits  = (const float2*)d_in[2];  // pred_logits   (B, Q, 2)
    // d_in[3] = batch_indices (layout is repeat(arange(B), P) -> implicit)
    const int*    src_idx = (const int*)d_in[4];     // (B, P)
    const int*    ihp     = (const int*)d_in[5];     // img_h scalar
    const int*    iwp     = (const int*)d_in[6];     // img_w scalar

    int*   flags = (int*)d_ws;
    float* acc   = (float*)((char*)d_ws + (size_t)BB * QQ * sizeof(int));
    float* out   = (float*)d_out;

    k_zero<<<(BB * QQ + 255) / 256, 256, 0, stream>>>(flags, acc);
    k_scatter<<<(NPTS + 255) / 256, 256, 0, stream>>>(src_idx, flags);
    k_ce<<<(BB * QQ) / 256, 256, 0, stream>>>(logits, flags, acc);
    k_points<<<dim3(BB, PP / 256), 256, 0, stream>>>(tpts, spts, ihp, iwp, acc);
    k_final<<<1, 1, 0, stream>>>(acc, out);
}

// Round 2
// 77.881 us; speedup vs baseline: 1.3628x; 1.3628x over previous
//
#include <hip/hip_runtime.h>
#include <math.h>

// Problem constants (from setup_inputs: B=8, P=512, Q=4096, H=W=512)
#define BB   8
#define PP   512
#define QQ   4096
#define NPTS (BB * PP)
#define RADF 45.0f              // truncation radius of gaussian patch
#define INV2S2 (1.0f / 450.0f)  // 1/(2*15^2)

// ws layout (floats): [0..63] CE partials (32 blocks x {num,den});
//                     [64..127] point-loss partials (64 blocks)
// Every slot is written unconditionally each call -> poison-safe, no init kernel.

// block-wide sum reduction (blockDim.x multiple of 64, <=512); valid at tid 0.
__device__ inline float block_reduce(float v, float* sbuf) {
#pragma unroll
    for (int off = 32; off > 0; off >>= 1) v += __shfl_down(v, off);
    const int lane = threadIdx.x & 63;
    const int wid  = threadIdx.x >> 6;
    __syncthreads();
    if (lane == 0) sbuf[wid] = v;
    __syncthreads();
    float r = (threadIdx.x < (blockDim.x >> 6)) ? sbuf[threadIdx.x] : 0.0f;
    if (wid == 0) {
#pragma unroll
        for (int off = 32; off > 0; off >>= 1) r += __shfl_down(r, off);
    }
    return r;
}

// ---------------------------------------------------------------------------
// CE loss: per-batch membership bitmask built in LDS (no global flags pass).
// grid (B, 4) x 256 threads; each block: 1024 queries of batch b.
__global__ void k_ce(const float2* __restrict__ logits, const int* __restrict__ src_idx,
                     float* __restrict__ part) {
    __shared__ unsigned int mask[QQ / 32];   // 4096 bits = 128 words
    __shared__ float sbuf[8];
    const int b = blockIdx.x, chunk = blockIdx.y;

    if (threadIdx.x < QQ / 32) mask[threadIdx.x] = 0u;
    __syncthreads();
    for (int j = threadIdx.x; j < PP; j += blockDim.x) {
        int q = src_idx[b * PP + j];
        atomicOr(&mask[q >> 5], 1u << (q & 31));   // idempotent: handles dup idx
    }
    __syncthreads();

    float num = 0.0f, den = 0.0f;
#pragma unroll
    for (int i = 0; i < 4; ++i) {
        int q = chunk * 1024 + i * 256 + threadIdx.x;
        float2 l = logits[b * QQ + q];
        int tc = (mask[q >> 5] >> (q & 31)) & 1;
        float mx  = fmaxf(l.x, l.y);
        float lse = mx + log1pf(expf(-fabsf(l.x - l.y)));
        float nll = lse - (tc ? l.y : l.x);
        float w   = tc ? 1.0f : 0.5f;
        num += w * nll;
        den += w;
    }
    num = block_reduce(num, sbuf);
    den = block_reduce(den, sbuf);
    if (threadIdx.x == 0) {
        int s = b * 4 + chunk;
        part[2 * s]     = num;
        part[2 * s + 1] = den;
    }
}

// ---------------------------------------------------------------------------
// Point loss. grid (B, 8) x 512 threads (8 waves). Wave c handles point-chunk
// c (64 points, wave-uniform m -> LDS broadcast) for 64 queries (qi = lane).
// Partial mins combined through LDS; chunk-0 wave finishes (its wx/wy are the
// right ones for query qi = t).
__global__ void k_points(const float* __restrict__ tpts, const float* __restrict__ spts,
                         const int* __restrict__ ihp, const int* __restrict__ iwp,
                         float* __restrict__ part) {
    __shared__ float spx[PP], spy[PP];
    __shared__ float pm[4][PP];              // [corner][c*64 + qi]
    const int b = blockIdx.x, g = blockIdx.y;
    const float fH = (float)ihp[0];
    const float fW = (float)iwp[0];
    const int t = threadIdx.x;

    // stage rounded/clipped target pixel coords (512 threads <-> 512 points)
    {
        float t0 = tpts[(b * PP + t) * 2 + 0];
        float t1 = tpts[(b * PP + t) * 2 + 1];
        float fx = rintf(t0 / fH * fW);      // round-half-even = jnp.round
        float fy = rintf(t1 / fW * fH);
        spx[t] = fminf(fmaxf(fx, 0.0f), fW - 1.0f);
        spy[t] = fminf(fmaxf(fy, 0.0f), fH - 1.0f);
    }
    __syncthreads();

    const int qi = t & 63, c = t >> 6;
    const int n = b * PP + g * 64 + qi;
    float sx = fminf(fmaxf(spts[n * 2 + 0] * fW, 0.0f), fW - 1.0f);
    float sy = fminf(fmaxf(spts[n * 2 + 1] * fH, 0.0f), fH - 1.0f);
    float x0 = floorf(sx), y0 = floorf(sy);
    float x1 = fminf(x0 + 1.0f, fW - 1.0f);
    float y1 = fminf(y0 + 1.0f, fH - 1.0f);
    float wx = sx - x0, wy = sy - y0;

    float m00 = 1e30f, m01 = 1e30f, m10 = 1e30f, m11 = 1e30f;
#pragma unroll 4
    for (int m = c * 64; m < c * 64 + 64; ++m) {
        float px = spx[m], py = spy[m];      // wave-uniform addr -> broadcast
        float dx0 = x0 - px, dx1 = x1 - px;
        float dy0 = y0 - py, dy1 = y1 - py;
        float cx0 = (fabsf(dx0) <= RADF) ? dx0 * dx0 : 1e30f;
        float cx1 = (fabsf(dx1) <= RADF) ? dx1 * dx1 : 1e30f;
        float cy0 = (fabsf(dy0) <= RADF) ? dy0 * dy0 : 1e30f;
        float cy1 = (fabsf(dy1) <= RADF) ? dy1 * dy1 : 1e30f;
        m00 = fminf(m00, cx0 + cy0);
        m01 = fminf(m01, cx1 + cy0);
        m10 = fminf(m10, cx0 + cy1);
        m11 = fminf(m11, cx1 + cy1);
    }
    pm[0][c * 64 + qi] = m00;
    pm[1][c * 64 + qi] = m01;
    pm[2][c * 64 + qi] = m10;
    pm[3][c * 64 + qi] = m11;
    __syncthreads();

    if (t < 64) {                            // chunk-0 wave: qi == t, own wx/wy valid
        float a00 = 1e30f, a01 = 1e30f, a10 = 1e30f, a11 = 1e30f;
#pragma unroll
        for (int cc = 0; cc < 8; ++cc) {
            a00 = fminf(a00, pm[0][cc * 64 + t]);
            a01 = fminf(a01, pm[1][cc * 64 + t]);
            a10 = fminf(a10, pm[2][cc * 64 + t]);
            a11 = fminf(a11, pm[3][cc * 64 + t]);
        }
        float v00 = (a00 < 1e29f) ? expf(-a00 * INV2S2) : 0.0f;
        float v01 = (a01 < 1e29f) ? expf(-a01 * INV2S2) : 0.0f;
        float v10 = (a10 < 1e29f) ? expf(-a10 * INV2S2) : 0.0f;
        float v11 = (a11 < 1e29f) ? expf(-a11 * INV2S2) : 0.0f;
        float p = v00 * (1.0f - wx) * (1.0f - wy) + v01 * wx * (1.0f - wy)
                + v10 * (1.0f - wx) * wy          + v11 * wx * wy;
        float om  = 1.0f - p;
        float raw = -(om * om) * logf(fmaxf(p, 1e-6f));
#pragma unroll
        for (int off = 32; off > 0; off >>= 1) raw += __shfl_down(raw, off);
        if (t == 0) part[64 + b * 8 + g] = raw;
    }
}

// ---------------------------------------------------------------------------
__global__ void k_final(const float* __restrict__ part, float* __restrict__ out) {
    const int t = threadIdx.x;               // 64 threads
    float num = (t < 32) ? part[2 * t]     : 0.0f;
    float den = (t < 32) ? part[2 * t + 1] : 0.0f;
    float pts = part[64 + t];
#pragma unroll
    for (int off = 32; off > 0; off >>= 1) {
        num += __shfl_down(num, off);
        den += __shfl_down(den, off);
        pts += __shfl_down(pts, off);
    }
    // total = ce_num/ce_den + 5.0 * (0.1 * focal_sum / N)
    if (t == 0) out[0] = num / den + 0.5f * pts / (float)NPTS;
}

// ---------------------------------------------------------------------------
extern "C" void kernel_launch(void* const* d_in, const int* in_sizes, int n_in,
                              void* d_out, int out_size, void* d_ws, size_t ws_size,
                              hipStream_t stream) {
    const float*  tpts    = (const float*)d_in[0];   // target_points (B*P, 2)
    const float*  spts    = (const float*)d_in[1];   // src_points    (B*P, 2)
    const float2* logits  = (const float2*)d_in[2];  // pred_logits   (B, Q, 2)
    // d_in[3] = batch_indices: repeat(arange(B), P) -> implicit in indexing
    const int*    src_idx = (const int*)d_in[4];     // (B, P)
    const int*    ihp     = (const int*)d_in[5];     // img_h scalar
    const int*    iwp     = (const int*)d_in[6];     // img_w scalar

    float* part = (float*)d_ws;
    float* out  = (float*)d_out;

    k_ce    <<<dim3(BB, 4), 256, 0, stream>>>(logits, src_idx, part);
    k_points<<<dim3(BB, 8), 512, 0, stream>>>(tpts, spts, ihp, iwp, part);
    k_final <<<1, 64, 0, stream>>>(part, out);
}